// Round 6
// baseline (3164.786 us; speedup 1.0000x reference)
//
#include <hip/hip_runtime.h>
#include <hip/hip_fp16.h>
#include <cmath>

typedef _Float16 f16;
typedef _Float16 f16x8 __attribute__((ext_vector_type(8)));
typedef float f32x4 __attribute__((ext_vector_type(4)));
typedef unsigned long long u64;

constexpr int B = 128, T = 64, S = 80, H = 512;
constexpr int BH = B * H;      // 65536
constexpr int NWG = 512;

#define LB256 __launch_bounds__(256)
#define MFMA16(a, b, c) __builtin_amdgcn_mfma_f32_16x16x32_f16(a, b, c, 0, 0, 0)

// ---- agent-scope write-through / uncached accessors ------------------------
__device__ __forceinline__ void astore4(void* p, unsigned v) {
    __hip_atomic_store((unsigned*)p, v, __ATOMIC_RELAXED, __HIP_MEMORY_SCOPE_AGENT);
}
__device__ __forceinline__ void astore8(void* p, u64 v) {
    __hip_atomic_store((u64*)p, v, __ATOMIC_RELAXED, __HIP_MEMORY_SCOPE_AGENT);
}
__device__ __forceinline__ unsigned aload4(const void* p) {
    return __hip_atomic_load((const unsigned*)p, __ATOMIC_RELAXED, __HIP_MEMORY_SCOPE_AGENT);
}

// ---- per-mslice single-hop barrier (128 WGs) -------------------------------
// arrive: write-through store to own padded slot (16B spacing, 32 lines).
// every thread <128 polls one slot directly -> one MALL round trip, no
// collector hop. __syncthreads before arrival drains vmcnt so phase stores
// are at the MALL first.
__device__ __forceinline__ void mbar(unsigned* slots, unsigned e,
                                     int mslice, int nslice) {
    __syncthreads();
    if (threadIdx.x == 0) astore4(&slots[(mslice * 128 + nslice) * 4], e);
    if (threadIdx.x < 128) {
        while (aload4(&slots[(mslice * 128 + threadIdx.x) * 4]) < e)
            __builtin_amdgcn_s_sleep(1);
    }
    __syncthreads();
    asm volatile("" ::: "memory");   // block load hoisting above the spin
}

// ---------------------------------------------------------------------------
__global__ LB256 void prep_all(
    const float* __restrict__ Wih0, const float* __restrict__ Whh0,
    const float* __restrict__ Wih1, const float* __restrict__ Whh1,
    const float* __restrict__ Wout, const float* __restrict__ Win,
    const float* __restrict__ bih0, const float* __restrict__ bhh0,
    const float* __restrict__ bih1, const float* __restrict__ bhh1,
    const float* __restrict__ h0,
    f16* __restrict__ WB0a, f16* __restrict__ WB0x, f16* __restrict__ WB1p,
    f16* __restrict__ WoutRf, f16* __restrict__ WcatT,
    float* __restrict__ bsum0, float* __restrict__ bsum1,
    f16* __restrict__ h0q, f16* __restrict__ h1q, f16* __restrict__ xq,
    unsigned* __restrict__ slots)
{
    int stride = gridDim.x * blockDim.x;
    int idx = blockIdx.x * blockDim.x + threadIdx.x;
    // row' = h*4+g gate-interleaved.  WB0a[row'][k] = Wih0[g*512+h][k]  (emb part)
    for (int i = idx; i < 2048 * 512; i += stride) {
        int rp = i >> 9, k = i & 511;
        int h = rp >> 2, g = rp & 3, src = g * 512 + h;
        WB0a[i] = (f16)Wih0[src * 1024 + k];
    }
    // WB0x[row'][k]: k<512 -> Wih0[src][512+k] (xprev), else Whh0[src][k-512]
    for (int i = idx; i < 2048 * 1024; i += stride) {
        int rp = i >> 10, k = i & 1023;
        int h = rp >> 2, g = rp & 3, src = g * 512 + h;
        float v = (k < 512) ? Wih0[src * 1024 + 512 + k] : Whh0[src * 512 + (k - 512)];
        WB0x[i] = (f16)v;
    }
    // WB1p[row'][k]: k<512 Wih1 else Whh1
    for (int i = idx; i < 2048 * 1024; i += stride) {
        int rp = i >> 10, k = i & 1023;
        int h = rp >> 2, g = rp & 3, src = g * 512 + h;
        float v = (k < 512) ? Wih1[src * 512 + k] : Whh1[src * 512 + (k - 512)];
        WB1p[i] = (f16)v;
    }
    // WoutRf[n][k] = W_out[n][512+k]
    for (int i = idx; i < 512 * 512; i += stride) {
        int n = i >> 9, k = i & 511;
        WoutRf[i] = (f16)Wout[n * 1024 + 512 + k];
    }
    // WcatT rows 0-511: Win^T; rows 512-1023: W_out left half
    for (int i = idx; i < 1024 * 512; i += stride) {
        int r = i >> 9, k = i & 511;
        float v = (r < 512) ? Win[k * 512 + r] : Wout[(r - 512) * 1024 + k];
        WcatT[i] = (f16)v;
    }
    for (int i = idx; i < 2048; i += stride) {
        bsum0[i] = bih0[i] + bhh0[i];
        bsum1[i] = bih1[i] + bhh1[i];
    }
    for (int i = idx; i < BH; i += stride) {
        h0q[i] = (f16)h0[i];        // ring slot 0
        h1q[i] = (f16)h0[BH + i];
        xq[i] = (f16)0.f;
    }
    for (int i = idx; i < 2048; i += stride) slots[i] = 0u;
}

__global__ LB256 void prep_emb(const int* __restrict__ tokens,
                               const float* __restrict__ embtab,
                               f16* __restrict__ embf16)
{
    int stride = gridDim.x * blockDim.x;
    for (int i = blockIdx.x * blockDim.x + threadIdx.x; i < T * B * 512; i += stride) {
        int e = i & 511;
        int tb = i >> 9;
        int tok = tokens[tb];
        embf16[i] = (f16)embtab[(size_t)tok * 512 + e];
    }
}

// ctxWV[m][j] = sum_k ctx_flat[m][k] * WcatT[j][k]
__global__ LB256 void gemm_ctx(const float* __restrict__ A32,
                               const f16* __restrict__ Wf,
                               f16* __restrict__ Cf)
{
    const int lane = threadIdx.x & 63;
    const int wave = threadIdx.x >> 6;
    const int quad = lane >> 4;
    const int wb = wave >> 1, wn = wave & 1;
    const int m = blockIdx.y * 32 + wb * 16 + (lane & 15);
    const int n = blockIdx.x * 32 + wn * 16 + (lane & 15);

    f32x4 acc = {0.f, 0.f, 0.f, 0.f};
    const float* ar = A32 + (size_t)m * 512;
    const f16* wr = Wf + (size_t)n * 512;
    #pragma unroll 4
    for (int i = 0; i < 16; ++i) {
        int k = i * 32 + quad * 8;
        float4 u0 = *(const float4*)(ar + k);
        float4 u1 = *(const float4*)(ar + k + 4);
        f16x8 av = { (f16)u0.x, (f16)u0.y, (f16)u0.z, (f16)u0.w,
                     (f16)u1.x, (f16)u1.y, (f16)u1.z, (f16)u1.w };
        f16x8 wv = *(const f16x8*)(wr + k);
        acc = MFMA16(av, wv, acc);
    }
    const int col = blockIdx.x * 32 + wn * 16 + (lane & 15);
    #pragma unroll
    for (int r = 0; r < 4; ++r) {
        int row = blockIdx.y * 32 + wb * 16 + quad * 4 + r;
        Cf[(size_t)row * 1024 + col] = (f16)acc[r];
    }
}

// ---------------------------------------------------------------------------
// persistent decoder: 512 WGs x 256 thr (2 WGs/CU), 3 per-mslice barriers/step.
// mslice = XCD pair (wg%8)/2 -> each group's data stays L2-resident on 2 XCDs.
__global__ __launch_bounds__(256, 2) void decoder_persist(
    const f16* __restrict__ embf16,   // [T][B][512]
    const f16* __restrict__ WB0a,     // [2048][512]  emb-part weights (L2)
    const f16* __restrict__ WB0x,     // [2048][1024] xprev|h0 weights -> LDS
    const f16* __restrict__ WB1p,     // [2048][1024] lstm1 weights -> LDS
    const f16* __restrict__ WoutRf,   // [512][512]   (L2)
    const f16* __restrict__ ctxWV,    // [B*S][1024]
    const float* __restrict__ bsum0, const float* __restrict__ bsum1,
    const float* __restrict__ c0in,   // [2][B][512]
    f16* __restrict__ h0q,            // [T+1][B][512] ring
    f16* __restrict__ h1q,            // [T+1][B][512] ring
    f16* __restrict__ xq,             // [T+1][B][512] ring
    unsigned* __restrict__ slots,
    float* __restrict__ out_outputs, float* __restrict__ out_attn,
    float* __restrict__ out_hT, float* __restrict__ out_cT)
{
    const int wg = blockIdx.x, tid = threadIdx.x;
    const int lane = tid & 63, wv_ = tid >> 6, quad = lane >> 4, m16 = lane & 15;
    // XCD-pair-aligned mapping: round-robin dispatch puts wg on XCD wg%8.
    const int mslice = (wg & 7) >> 1;            // 0..3   (32 b rows)
    const int nslice = ((wg >> 3) << 1) | (wg & 1);   // 0..127 (16 gate rows)
    const int b0 = mslice * 32;
    const int rowbase = nslice * 16;

    __shared__ f16 WLA[16 * 1024];       // xprev|h0 weights, XOR-swizzled
    __shared__ f16 WLB[16 * 1024];       // lstm1 weights
    __shared__ float gbuf[4][32][16];
    __shared__ float scf[80], pp[80];
    __shared__ float psum[2][128];
    __shared__ __align__(8) f16 h1s[512];
    __shared__ __align__(8) f16 obuf[128];

    // ---- one-time: weights -> LDS (granule g stored at g ^ (row&7)) ----
    for (int i = tid; i < 2048; i += 256) {
        int r = i >> 7, g = i & 127, gp = g ^ (r & 7);
        *(f16x8*)(WLA + (r * 128 + gp) * 8) =
            *(const f16x8*)(WB0x + ((size_t)(rowbase + r)) * 1024 + g * 8);
        *(f16x8*)(WLB + (r * 128 + gp) * 8) =
            *(const f16x8*)(WB1p + ((size_t)(rowbase + r)) * 1024 + g * 8);
    }
    // cell state registers: thread tid<64 owns (b = b0 + tid&31, h = nslice*4 + jp+{0,1})
    const int cb_ = b0 + (tid & 31);
    const int jp = (tid >> 5) * 2;       // 0 or 2 (tid<64)
    const int ch = nslice * 4 + jp;
    float c0r[2], c1r[2], bi0[2][4], bi1[2][4];
    if (tid < 64) {
        #pragma unroll
        for (int j = 0; j < 2; ++j) {
            c0r[j] = c0in[cb_ * 512 + ch + j];
            c1r[j] = c0in[BH + cb_ * 512 + ch + j];
            #pragma unroll
            for (int g = 0; g < 4; ++g) {
                bi0[j][g] = bsum0[g * 512 + ch + j];
                bi1[j][g] = bsum1[g * 512 + ch + j];
            }
        }
    }
    // phase C role: 4 WGs per batch row; q = n-quarter
    const int q = nslice & 3;
    const int bloc = nslice >> 2;        // 0..31
    const int cb2 = b0 + bloc;           // batch row for phase C
    unsigned ep = 0;
    __syncthreads();

    for (int t = 0; t < T; ++t) {
        const f16* EMBt = embf16 + (size_t)t * BH;
        const f16* XPt  = xq  + (size_t)t * BH;
        const f16* H0t  = h0q + (size_t)t * BH;
        const f16* H1t  = h1q + (size_t)t * BH;
        f16* H0n = h0q + (size_t)(t + 1) * BH;
        f16* H1n = h1q + (size_t)(t + 1) * BH;
        f16* XPn = xq  + (size_t)(t + 1) * BH;

        // ================= phase A: lstm0 gates, K=1536 k-split over waves ==
        {
            f32x4 ac0 = {0.f, 0.f, 0.f, 0.f}, ac1 = {0.f, 0.f, 0.f, 0.f};
            const int a0r = (b0 + m16) * 512 + quad * 8;
            const int a1r = (b0 + 16 + m16) * 512 + quad * 8;
            const f16* wga = WB0a + (size_t)(rowbase + m16) * 512 + quad * 8;
            const int gq = quad;
            if (wv_ == 0) {                      // emb k 0..384
                #pragma unroll
                for (int ks = 0; ks < 12; ++ks) {
                    int k = ks * 32;
                    f16x8 w = *(const f16x8*)(wga + k);
                    ac0 = MFMA16(*(const f16x8*)(EMBt + a0r + k), w, ac0);
                    ac1 = MFMA16(*(const f16x8*)(EMBt + a1r + k), w, ac1);
                }
            } else if (wv_ == 1) {               // emb 384..512 + xprev 0..256
                #pragma unroll
                for (int ks = 0; ks < 4; ++ks) {
                    int k = 384 + ks * 32;
                    f16x8 w = *(const f16x8*)(wga + k);
                    ac0 = MFMA16(*(const f16x8*)(EMBt + a0r + k), w, ac0);
                    ac1 = MFMA16(*(const f16x8*)(EMBt + a1r + k), w, ac1);
                }
                #pragma unroll
                for (int ks = 0; ks < 8; ++ks) {
                    int k = ks * 32;
                    int gr = (k >> 3) + gq, gp = gr ^ (m16 & 7);
                    f16x8 w = *(const f16x8*)(WLA + (m16 * 128 + gp) * 8);
                    ac0 = MFMA16(*(const f16x8*)(XPt + a0r + k), w, ac0);
                    ac1 = MFMA16(*(const f16x8*)(XPt + a1r + k), w, ac1);
                }
            } else if (wv_ == 2) {               // xprev 256..512 + h0r 0..128
                #pragma unroll
                for (int ks = 0; ks < 8; ++ks) {
                    int k = 256 + ks * 32;
                    int gr = (k >> 3) + gq, gp = gr ^ (m16 & 7);
                    f16x8 w = *(const f16x8*)(WLA + (m16 * 128 + gp) * 8);
                    ac0 = MFMA16(*(const f16x8*)(XPt + a0r + k), w, ac0);
                    ac1 = MFMA16(*(const f16x8*)(XPt + a1r + k), w, ac1);
                }
                #pragma unroll
                for (int ks = 0; ks < 4; ++ks) {
                    int k = ks * 32;
                    int gr = 64 + (k >> 3) + gq, gp = gr ^ (m16 & 7);
                    f16x8 w = *(const f16x8*)(WLA + (m16 * 128 + gp) * 8);
                    ac0 = MFMA16(*(const f16x8*)(H0t + a0r + k), w, ac0);
                    ac1 = MFMA16(*(const f16x8*)(H0t + a1r + k), w, ac1);
                }
            } else {                             // h0r 128..512
                #pragma unroll
                for (int ks = 0; ks < 12; ++ks) {
                    int k = 128 + ks * 32;
                    int gr = 64 + (k >> 3) + gq, gp = gr ^ (m16 & 7);
                    f16x8 w = *(const f16x8*)(WLA + (m16 * 128 + gp) * 8);
                    ac0 = MFMA16(*(const f16x8*)(H0t + a0r + k), w, ac0);
                    ac1 = MFMA16(*(const f16x8*)(H0t + a1r + k), w, ac1);
                }
            }
            #pragma unroll
            for (int r = 0; r < 4; ++r) {
                gbuf[wv_][quad * 4 + r][m16] = ac0[r];
                gbuf[wv_][16 + quad * 4 + r][m16] = ac1[r];
            }
            __syncthreads();
            if (tid < 64) {
                const int bl = tid & 31;
                float hv[2];
                #pragma unroll
                for (int j = 0; j < 2; ++j) {
                    int nl = (jp + j) * 4;
                    float z[4];
                    #pragma unroll
                    for (int g = 0; g < 4; ++g)
                        z[g] = gbuf[0][bl][nl + g] + gbuf[1][bl][nl + g] +
                               gbuf[2][bl][nl + g] + gbuf[3][bl][nl + g] + bi0[j][g];
                    float ig = 1.f / (1.f + expf(-z[0]));
                    float fg = 1.f / (1.f + expf(-z[1]));
                    float gg = tanhf(z[2]);
                    float og = 1.f / (1.f + expf(-z[3]));
                    float c = fg * c0r[j] + ig * gg;
                    c0r[j] = c;
                    hv[j] = og * tanhf(c);
                }
                union { f16 f[2]; unsigned u; } pk;
                pk.f[0] = (f16)hv[0]; pk.f[1] = (f16)hv[1];
                astore4(H0n + cb_ * 512 + ch, pk.u);
                if (t == T - 1) {
                    out_hT[cb_ * 512 + ch] = hv[0];
                    out_hT[cb_ * 512 + ch + 1] = hv[1];
                    out_cT[cb_ * 512 + ch] = c0r[0];
                    out_cT[cb_ * 512 + ch + 1] = c0r[1];
                }
            }
        }
        mbar(slots, ++ep, mslice, nslice);

        // ================= phase B: lstm1 gates, K=1024 =================
        {
            f32x4 ac0 = {0.f, 0.f, 0.f, 0.f}, ac1 = {0.f, 0.f, 0.f, 0.f};
            const int a0r = (b0 + m16) * 512 + quad * 8;
            const int a1r = (b0 + 16 + m16) * 512 + quad * 8;
            const f16* Asrc = (wv_ < 2) ? H0n : H1t;
            const int k0 = (wv_ & 1) * 256;
            const int gbase = ((wv_ < 2) ? 0 : 64) + (k0 >> 3);
            #pragma unroll
            for (int ks = 0; ks < 8; ++ks) {
                int k = k0 + ks * 32;
                int gr = gbase + ks * 4 + quad, gp = gr ^ (m16 & 7);
                f16x8 w = *(const f16x8*)(WLB + (m16 * 128 + gp) * 8);
                ac0 = MFMA16(*(const f16x8*)(Asrc + a0r + k), w, ac0);
                ac1 = MFMA16(*(const f16x8*)(Asrc + a1r + k), w, ac1);
            }
            #pragma unroll
            for (int r = 0; r < 4; ++r) {
                gbuf[wv_][quad * 4 + r][m16] = ac0[r];
                gbuf[wv_][16 + quad * 4 + r][m16] = ac1[r];
            }
            __syncthreads();
            if (tid < 64) {
                const int bl = tid & 31;
                float hv[2];
                #pragma unroll
                for (int j = 0; j < 2; ++j) {
                    int nl = (jp + j) * 4;
                    float z[4];
                    #pragma unroll
                    for (int g = 0; g < 4; ++g)
                        z[g] = gbuf[0][bl][nl + g] + gbuf[1][bl][nl + g] +
                               gbuf[2][bl][nl + g] + gbuf[3][bl][nl + g] + bi1[j][g];
                    float ig = 1.f / (1.f + expf(-z[0]));
                    float fg = 1.f / (1.f + expf(-z[1]));
                    float gg = tanhf(z[2]);
                    float og = 1.f / (1.f + expf(-z[3]));
                    float c = fg * c1r[j] + ig * gg;
                    c1r[j] = c;
                    hv[j] = og * tanhf(c);
                }
                union { f16 f[2]; unsigned u; } pk;
                pk.f[0] = (f16)hv[0]; pk.f[1] = (f16)hv[1];
                astore4(H1n + cb_ * 512 + ch, pk.u);
                if (t == T - 1) {
                    out_hT[BH + cb_ * 512 + ch] = hv[0];
                    out_hT[BH + cb_ * 512 + ch + 1] = hv[1];
                    out_cT[BH + cb_ * 512 + ch] = c1r[0];
                    out_cT[BH + cb_ * 512 + ch + 1] = c1r[1];
                }
            }
        }
        mbar(slots, ++ep, mslice, nslice);

        // ===== phase C: scores(x4 redundant) + softmax + output slice ======
        {
            // h1 row -> LDS (fresh ring address, cached loads are safe)
            if (tid < 128)
                ((u64*)h1s)[tid] = ((const u64*)(H1n + cb2 * 512))[tid];
            __syncthreads();
            // scores: wave wv_ computes s = wv_*20 .. +20 (all 80 in-WG)
            f16x8 hfrag = *(const f16x8*)&h1s[lane * 8];
            #pragma unroll 4
            for (int i = 0; i < 20; ++i) {
                int s = wv_ * 20 + i;
                const f16* cr = ctxWV + ((size_t)(cb2 * 80 + s)) * 1024 + lane * 8;
                f16x8 a = *(const f16x8*)cr;
                float d = 0.f;
                #pragma unroll
                for (int j = 0; j < 8; ++j) d += (float)a[j] * (float)hfrag[j];
                #pragma unroll
                for (int o = 32; o > 0; o >>= 1) d += __shfl_xor(d, o);
                if (lane == 0) scf[s] = d;
            }
            __syncthreads();
            if (wv_ == 0) {
                float e0 = scf[lane];
                float e1 = (lane < 16) ? scf[64 + lane] : -1e30f;
                float m = fmaxf(e0, e1);
                #pragma unroll
                for (int o = 32; o > 0; o >>= 1) m = fmaxf(m, __shfl_xor(m, o));
                float x0 = expf(e0 - m);
                float x1 = (lane < 16) ? expf(e1 - m) : 0.f;
                float su = x0 + x1;
                #pragma unroll
                for (int o = 32; o > 0; o >>= 1) su += __shfl_xor(su, o);
                float inv = 1.f / su;
                float p0 = x0 * inv;
                pp[lane] = p0;
                if (q == 0) out_attn[((size_t)t * 128 + cb2) * 80 + lane] = p0;
                if (lane < 16) {
                    float p1 = x1 * inv;
                    pp[64 + lane] = p1;
                    if (q == 0) out_attn[((size_t)t * 128 + cb2) * 80 + 64 + lane] = p1;
                }
            }
            __syncthreads();
            // out[n] for n in [q*128, q*128+128): ctxV reduce + WoutR dot,
            // K split over thread halves, combined in LDS.
            const int nl = tid & 127, kh = tid >> 7;
            const int n = q * 128 + nl;
            float acc = 0.f;
            if (kh == 0) {
                const f16* cv = ctxWV + (size_t)cb2 * 80 * 1024 + 512 + n;
                #pragma unroll 8
                for (int s = 0; s < 80; ++s) acc += pp[s] * (float)cv[(size_t)s * 1024];
                const f16* wr = WoutRf + (size_t)n * 512;
                #pragma unroll
                for (int kk = 0; kk < 24; ++kk) {
                    f16x8 w = *(const f16x8*)(wr + kk * 8);
                    f16x8 h = *(const f16x8*)&h1s[kk * 8];
                    #pragma unroll
                    for (int j = 0; j < 8; ++j) acc += (float)w[j] * (float)h[j];
                }
            } else {
                const f16* wr = WoutRf + (size_t)n * 512;
                #pragma unroll
                for (int kk = 24; kk < 64; ++kk) {
                    f16x8 w = *(const f16x8*)(wr + kk * 8);
                    f16x8 h = *(const f16x8*)&h1s[kk * 8];
                    #pragma unroll
                    for (int j = 0; j < 8; ++j) acc += (float)w[j] * (float)h[j];
                }
            }
            psum[kh][nl] = acc;
            __syncthreads();
            if (tid < 128) {
                float o = tanhf(psum[0][tid] + psum[1][tid]);
                out_outputs[(size_t)t * BH + cb2 * 512 + n] = o;
                obuf[tid] = (f16)o;
            }
            __syncthreads();
            if (tid < 32)
                astore8(XPn + cb2 * 512 + q * 128 + tid * 4, ((const u64*)obuf)[tid]);
        }
        mbar(slots, ++ep, mslice, nslice);
    }
}

// ---------------------------------------------------------------------------
extern "C" void kernel_launch(void* const* d_in, const int* in_sizes, int n_in,
                              void* d_out, int out_size, void* d_ws, size_t ws_size,
                              hipStream_t stream)
{
    const int*   tokens  = (const int*)  d_in[0];
    const float* h0      = (const float*)d_in[1];
    const float* c0      = (const float*)d_in[2];
    const float* context = (const float*)d_in[3];
    const float* embtab  = (const float*)d_in[4];
    const float* Wih0    = (const float*)d_in[5];
    const float* Whh0    = (const float*)d_in[6];
    const float* bih0    = (const float*)d_in[7];
    const float* bhh0    = (const float*)d_in[8];
    const float* Wih1    = (const float*)d_in[9];
    const float* Whh1    = (const float*)d_in[10];
    const float* bih1    = (const float*)d_in[11];
    const float* bhh1    = (const float*)d_in[12];
    const float* Win     = (const float*)d_in[13];
    const float* Wout    = (const float*)d_in[14];

    float* outF        = (float*)d_out;
    float* out_outputs = outF;
    float* out_hT      = outF + (size_t)T * BH;
    float* out_cT      = out_hT + 2 * BH;
    float* out_attn    = out_cT + 2 * BH;

    char* w = (char*)d_ws;
    auto alloc = [&](size_t bytes) {
        char* p = w;
        w += (bytes + 255) & ~(size_t)255;
        return p;
    };
    f16*      WB0a   = (f16*)     alloc((size_t)2048 * 512 * 2);
    f16*      WB0x   = (f16*)     alloc((size_t)2048 * 1024 * 2);
    f16*      WB1p   = (f16*)     alloc((size_t)2048 * 1024 * 2);
    f16*      WoutRf = (f16*)     alloc((size_t)512 * 512 * 2);
    f16*      WcatT  = (f16*)     alloc((size_t)1024 * 512 * 2);
    f16*      embf16 = (f16*)     alloc((size_t)T * B * 512 * 2);
    f16*      ctxWV  = (f16*)     alloc((size_t)B * S * 1024 * 2);
    float*    bsum0  = (float*)   alloc(2048 * 4);
    float*    bsum1  = (float*)   alloc(2048 * 4);
    f16*      h0q    = (f16*)     alloc((size_t)(T + 1) * BH * 2);
    f16*      h1q    = (f16*)     alloc((size_t)(T + 1) * BH * 2);
    f16*      xq     = (f16*)     alloc((size_t)(T + 1) * BH * 2);
    unsigned* slots  = (unsigned*)alloc(2048 * 4);

    prep_all<<<1024, 256, 0, stream>>>(Wih0, Whh0, Wih1, Whh1, Wout, Win,
                                       bih0, bhh0, bih1, bhh1, h0,
                                       WB0a, WB0x, WB1p, WoutRf, WcatT,
                                       bsum0, bsum1, h0q, h1q, xq, slots);
    prep_emb<<<2048, 256, 0, stream>>>(tokens, embtab, embf16);
    gemm_ctx<<<dim3(32, 320), 256, 0, stream>>>(context, WcatT, ctxWV);

    decoder_persist<<<NWG, 256, 0, stream>>>(
        embf16, WB0a, WB0x, WB1p, WoutRf, ctxWV, bsum0, bsum1, c0,
        h0q, h1q, xq, slots,
        out_outputs, out_attn, out_hT, out_cT);
}

// Round 8
// 2035.886 us; speedup vs baseline: 1.5545x; 1.5545x over previous
//
#include <hip/hip_runtime.h>
#include <hip/hip_fp16.h>
#include <cmath>

typedef _Float16 f16;
typedef _Float16 f16x8 __attribute__((ext_vector_type(8)));
typedef float f32x4 __attribute__((ext_vector_type(4)));
typedef unsigned long long u64;

constexpr int B = 128, T = 64, S = 80, H = 512;
constexpr int BH = B * H;      // 65536
constexpr int NWG = 512;

#define LB256 __launch_bounds__(256)
#define MFMA16(a, b, c) __builtin_amdgcn_mfma_f32_16x16x32_f16(a, b, c, 0, 0, 0)

// ---- agent-scope write-through / uncached accessors ------------------------
__device__ __forceinline__ void astore4(void* p, unsigned v) {
    __hip_atomic_store((unsigned*)p, v, __ATOMIC_RELAXED, __HIP_MEMORY_SCOPE_AGENT);
}
__device__ __forceinline__ void astoref(float* p, float v) {
    __hip_atomic_store(p, v, __ATOMIC_RELAXED, __HIP_MEMORY_SCOPE_AGENT);
}
__device__ __forceinline__ void astore8(void* p, u64 v) {
    __hip_atomic_store((u64*)p, v, __ATOMIC_RELAXED, __HIP_MEMORY_SCOPE_AGENT);
}
__device__ __forceinline__ u64 aload8(const void* p) {
    return __hip_atomic_load((const u64*)p, __ATOMIC_RELAXED, __HIP_MEMORY_SCOPE_AGENT);
}
__device__ __forceinline__ unsigned aload4(const void* p) {
    return __hip_atomic_load((const unsigned*)p, __ATOMIC_RELAXED, __HIP_MEMORY_SCOPE_AGENT);
}

// ---- distributed epoch barrier (global, collector two-hop) — R5-proven ----
__device__ __forceinline__ void dbar(unsigned* slots, unsigned* go,
                                     unsigned e, int wg) {
    __syncthreads();
    if (threadIdx.x == 0) astore4(&slots[wg * 4], e);
    if (wg == NWG - 1) {
        const int i0 = threadIdx.x * 2;
        while (aload4(&slots[i0 * 4]) < e) __builtin_amdgcn_s_sleep(1);
        while (aload4(&slots[(i0 + 1) * 4]) < e) __builtin_amdgcn_s_sleep(1);
        __syncthreads();
        if (threadIdx.x < 16) astore4(&go[threadIdx.x * 16], e);
    }
    if (threadIdx.x == 0) {
        while (aload4(&go[(wg & 15) * 16]) < e) __builtin_amdgcn_s_sleep(1);
    }
    __syncthreads();
    asm volatile("" ::: "memory");   // block load hoisting above the spin
}

// ---------------------------------------------------------------------------
__global__ LB256 void prep_all(
    const float* __restrict__ Wih0, const float* __restrict__ Whh0,
    const float* __restrict__ Wih1, const float* __restrict__ Whh1,
    const float* __restrict__ Wout, const float* __restrict__ Win,
    const float* __restrict__ bih0, const float* __restrict__ bhh0,
    const float* __restrict__ bih1, const float* __restrict__ bhh1,
    const float* __restrict__ h0,
    f16* __restrict__ WB0a, f16* __restrict__ WB0x, f16* __restrict__ WB1p,
    f16* __restrict__ WoutRf, f16* __restrict__ WcatT,
    float* __restrict__ bsum0, float* __restrict__ bsum1,
    f16* __restrict__ h0q, f16* __restrict__ h1q, f16* __restrict__ xq,
    unsigned* __restrict__ slots, unsigned* __restrict__ go)
{
    int stride = gridDim.x * blockDim.x;
    int idx = blockIdx.x * blockDim.x + threadIdx.x;
    // row' = h*4+g gate-interleaved.  WB0a[row'][k] = Wih0[g*512+h][k]  (emb part)
    for (int i = idx; i < 2048 * 512; i += stride) {
        int rp = i >> 9, k = i & 511;
        int h = rp >> 2, g = rp & 3, src = g * 512 + h;
        WB0a[i] = (f16)Wih0[src * 1024 + k];
    }
    // WB0x[row'][k]: k<512 -> Wih0[src][512+k] (xprev), else Whh0[src][k-512]
    for (int i = idx; i < 2048 * 1024; i += stride) {
        int rp = i >> 10, k = i & 1023;
        int h = rp >> 2, g = rp & 3, src = g * 512 + h;
        float v = (k < 512) ? Wih0[src * 1024 + 512 + k] : Whh0[src * 512 + (k - 512)];
        WB0x[i] = (f16)v;
    }
    // WB1p[row'][k]: k<512 Wih1 else Whh1
    for (int i = idx; i < 2048 * 1024; i += stride) {
        int rp = i >> 10, k = i & 1023;
        int h = rp >> 2, g = rp & 3, src = g * 512 + h;
        float v = (k < 512) ? Wih1[src * 512 + k] : Whh1[src * 512 + (k - 512)];
        WB1p[i] = (f16)v;
    }
    // WoutRf[n][k] = W_out[n][512+k]
    for (int i = idx; i < 512 * 512; i += stride) {
        int n = i >> 9, k = i & 511;
        WoutRf[i] = (f16)Wout[n * 1024 + 512 + k];
    }
    // WcatT rows 0-511: Win^T; rows 512-1023: W_out left half
    for (int i = idx; i < 1024 * 512; i += stride) {
        int r = i >> 9, k = i & 511;
        float v = (r < 512) ? Win[k * 512 + r] : Wout[(r - 512) * 1024 + k];
        WcatT[i] = (f16)v;
    }
    for (int i = idx; i < 2048; i += stride) {
        bsum0[i] = bih0[i] + bhh0[i];
        bsum1[i] = bih1[i] + bhh1[i];
    }
    for (int i = idx; i < BH; i += stride) {
        h0q[i] = (f16)h0[i];        // ring slot 0
        h1q[i] = (f16)h0[BH + i];
        xq[i] = (f16)0.f;
    }
    for (int i = idx; i < 2048; i += stride) slots[i] = 0u;
    for (int i = idx; i < 256; i += stride) go[i] = 0u;
}

__global__ LB256 void prep_emb(const int* __restrict__ tokens,
                               const float* __restrict__ embtab,
                               f16* __restrict__ embf16)
{
    int stride = gridDim.x * blockDim.x;
    for (int i = blockIdx.x * blockDim.x + threadIdx.x; i < T * B * 512; i += stride) {
        int e = i & 511;
        int tb = i >> 9;
        int tok = tokens[tb];
        embf16[i] = (f16)embtab[(size_t)tok * 512 + e];
    }
}

// ctxWV[m][j] = sum_k ctx_flat[m][k] * WcatT[j][k]
__global__ LB256 void gemm_ctx(const float* __restrict__ A32,
                               const f16* __restrict__ Wf,
                               f16* __restrict__ Cf)
{
    const int lane = threadIdx.x & 63;
    const int wave = threadIdx.x >> 6;
    const int quad = lane >> 4;
    const int wb = wave >> 1, wn = wave & 1;
    const int m = blockIdx.y * 32 + wb * 16 + (lane & 15);
    const int n = blockIdx.x * 32 + wn * 16 + (lane & 15);

    f32x4 acc = {0.f, 0.f, 0.f, 0.f};
    const float* ar = A32 + (size_t)m * 512;
    const f16* wr = Wf + (size_t)n * 512;
    #pragma unroll 4
    for (int i = 0; i < 16; ++i) {
        int k = i * 32 + quad * 8;
        float4 u0 = *(const float4*)(ar + k);
        float4 u1 = *(const float4*)(ar + k + 4);
        f16x8 av = { (f16)u0.x, (f16)u0.y, (f16)u0.z, (f16)u0.w,
                     (f16)u1.x, (f16)u1.y, (f16)u1.z, (f16)u1.w };
        f16x8 wv = *(const f16x8*)(wr + k);
        acc = MFMA16(av, wv, acc);
    }
    const int col = blockIdx.x * 32 + wn * 16 + (lane & 15);
    #pragma unroll
    for (int r = 0; r < 4; ++r) {
        int row = blockIdx.y * 32 + wb * 16 + quad * 4 + r;
        Cf[(size_t)row * 1024 + col] = (f16)acc[r];
    }
}

// ---------------------------------------------------------------------------
// persistent decoder: 512 WGs x 256 thr (2 WGs/CU), 4 global epoch barriers.
// R5 structure; ONLY the C-phase roles are permuted so WG on XCD x=wg&7
// handles attention for b in [16x,16x+16) -> ctxWV slice 2.6MB stays L2-local.
__global__ __launch_bounds__(256, 2) void decoder_persist(
    const f16* __restrict__ embf16,   // [T][B][512]
    const f16* __restrict__ WB0a,     // [2048][512]  emb-part weights (L2)
    const f16* __restrict__ WB0x,     // [2048][1024] xprev|h0 weights -> LDS
    const f16* __restrict__ WB1p,     // [2048][1024] lstm1 weights -> LDS
    const f16* __restrict__ WoutRf,   // [512][512]   (L2)
    const f16* __restrict__ ctxWV,    // [B*S][1024]
    const float* __restrict__ bsum0, const float* __restrict__ bsum1,
    const float* __restrict__ c0in,   // [2][B][512]
    f16* __restrict__ h0q,            // [T+1][B][512] ring
    f16* __restrict__ h1q,            // [T+1][B][512] ring
    f16* __restrict__ xq,             // [T+1][B][512] ring
    float* __restrict__ scb,          // [B][80]   (uncached path)
    f16* __restrict__ out2b,          // [B][512]  (uncached path)
    unsigned* __restrict__ slots, unsigned* __restrict__ go,
    float* __restrict__ out_outputs, float* __restrict__ out_attn,
    float* __restrict__ out_hT, float* __restrict__ out_cT)
{
    const int wg = blockIdx.x, tid = threadIdx.x;
    const int lane = tid & 63, wv_ = tid >> 6, quad = lane >> 4, m16 = lane & 15;
    const int mslice = wg >> 7;          // 0..3   (32 b rows)
    const int nslice = wg & 127;         // 0..127 (16 gate rows)
    const int b0 = mslice * 32;
    const int rowbase = nslice * 16;

    __shared__ f16 WLA[16 * 1024];       // xprev|h0 weights, XOR-swizzled
    __shared__ f16 WLB[16 * 1024];       // lstm1 weights
    __shared__ float gbuf[4][32][16];
    __shared__ float scf[80], pp[80];
    __shared__ unsigned o2buf[128];
    __shared__ f16 obuf[256];

    // ---- one-time: weights -> LDS (granule g stored at g ^ (row&7)) ----
    for (int i = tid; i < 2048; i += 256) {
        int r = i >> 7, g = i & 127, gp = g ^ (r & 7);
        *(f16x8*)(WLA + (r * 128 + gp) * 8) =
            *(const f16x8*)(WB0x + ((size_t)(rowbase + r)) * 1024 + g * 8);
        *(f16x8*)(WLB + (r * 128 + gp) * 8) =
            *(const f16x8*)(WB1p + ((size_t)(rowbase + r)) * 1024 + g * 8);
    }
    // cell state registers: thread tid<64 owns (b = b0 + tid&31, h = nslice*4 + jp+{0,1})
    const int cb_ = b0 + (tid & 31);
    const int jp = (tid >> 5) * 2;       // 0 or 2 (tid<64)
    const int ch = nslice * 4 + jp;
    float c0r[2], c1r[2], bi0[2][4], bi1[2][4];
    if (tid < 64) {
        #pragma unroll
        for (int j = 0; j < 2; ++j) {
            c0r[j] = c0in[cb_ * 512 + ch + j];
            c1r[j] = c0in[BH + cb_ * 512 + ch + j];
            #pragma unroll
            for (int g = 0; g < 4; ++g) {
                bi0[j][g] = bsum0[g * 512 + ch + j];
                bi1[j][g] = bsum1[g * 512 + ch + j];
            }
        }
    }
    // ---- XCD-local attention roles: x = wg&7 (XCD), r = wg>>3 (0..63) ----
    const int xid = wg & 7;
    const int xr = wg >> 3;
    // C1 scores (all WGs): 4 WGs per b of own XCD
    const int b_s = xid * 16 + (xr & 15);
    const int soff = (xr >> 4) * 20;
    // C1 out2 (xr<16): rows [xid*16, +16), cols [xr*32, +32)
    // C2 (16<=xr<48): b2 = xid*16 + (xr-16)>>1, half nh = (xr-16)&1
    const int b2 = xid * 16 + ((xr - 16) >> 1);
    const int nh = (xr - 16) & 1;
    unsigned ep = 0;
    __syncthreads();

    for (int t = 0; t < T; ++t) {
        const f16* EMBt = embf16 + (size_t)t * BH;
        const f16* XPt  = xq  + (size_t)t * BH;
        const f16* H0t  = h0q + (size_t)t * BH;
        const f16* H1t  = h1q + (size_t)t * BH;
        f16* H0n = h0q + (size_t)(t + 1) * BH;
        f16* H1n = h1q + (size_t)(t + 1) * BH;
        f16* XPn = xq  + (size_t)(t + 1) * BH;

        // ================= phase A: lstm0 gates, K=1536 k-split over waves ==
        {
            f32x4 ac0 = {0.f, 0.f, 0.f, 0.f}, ac1 = {0.f, 0.f, 0.f, 0.f};
            const int a0r = (b0 + m16) * 512 + quad * 8;
            const int a1r = (b0 + 16 + m16) * 512 + quad * 8;
            const f16* wga = WB0a + (size_t)(rowbase + m16) * 512 + quad * 8;
            const int gq = quad;
            if (wv_ == 0) {                      // emb k 0..384
                #pragma unroll
                for (int ks = 0; ks < 12; ++ks) {
                    int k = ks * 32;
                    f16x8 w = *(const f16x8*)(wga + k);
                    ac0 = MFMA16(*(const f16x8*)(EMBt + a0r + k), w, ac0);
                    ac1 = MFMA16(*(const f16x8*)(EMBt + a1r + k), w, ac1);
                }
            } else if (wv_ == 1) {               // emb 384..512 + xprev 0..256
                #pragma unroll
                for (int ks = 0; ks < 4; ++ks) {
                    int k = 384 + ks * 32;
                    f16x8 w = *(const f16x8*)(wga + k);
                    ac0 = MFMA16(*(const f16x8*)(EMBt + a0r + k), w, ac0);
                    ac1 = MFMA16(*(const f16x8*)(EMBt + a1r + k), w, ac1);
                }
                #pragma unroll
                for (int ks = 0; ks < 8; ++ks) {
                    int k = ks * 32;
                    int gr = (k >> 3) + gq, gp = gr ^ (m16 & 7);
                    f16x8 w = *(const f16x8*)(WLA + (m16 * 128 + gp) * 8);
                    ac0 = MFMA16(*(const f16x8*)(XPt + a0r + k), w, ac0);
                    ac1 = MFMA16(*(const f16x8*)(XPt + a1r + k), w, ac1);
                }
            } else if (wv_ == 2) {               // xprev 256..512 + h0r 0..128
                #pragma unroll
                for (int ks = 0; ks < 8; ++ks) {
                    int k = 256 + ks * 32;
                    int gr = (k >> 3) + gq, gp = gr ^ (m16 & 7);
                    f16x8 w = *(const f16x8*)(WLA + (m16 * 128 + gp) * 8);
                    ac0 = MFMA16(*(const f16x8*)(XPt + a0r + k), w, ac0);
                    ac1 = MFMA16(*(const f16x8*)(XPt + a1r + k), w, ac1);
                }
                #pragma unroll
                for (int ks = 0; ks < 4; ++ks) {
                    int k = ks * 32;
                    int gr = 64 + (k >> 3) + gq, gp = gr ^ (m16 & 7);
                    f16x8 w = *(const f16x8*)(WLA + (m16 * 128 + gp) * 8);
                    ac0 = MFMA16(*(const f16x8*)(H0t + a0r + k), w, ac0);
                    ac1 = MFMA16(*(const f16x8*)(H0t + a1r + k), w, ac1);
                }
            } else {                             // h0r 128..512
                #pragma unroll
                for (int ks = 0; ks < 12; ++ks) {
                    int k = 128 + ks * 32;
                    int gr = 64 + (k >> 3) + gq, gp = gr ^ (m16 & 7);
                    f16x8 w = *(const f16x8*)(WLA + (m16 * 128 + gp) * 8);
                    ac0 = MFMA16(*(const f16x8*)(H0t + a0r + k), w, ac0);
                    ac1 = MFMA16(*(const f16x8*)(H0t + a1r + k), w, ac1);
                }
            }
            #pragma unroll
            for (int r = 0; r < 4; ++r) {
                gbuf[wv_][quad * 4 + r][m16] = ac0[r];
                gbuf[wv_][16 + quad * 4 + r][m16] = ac1[r];
            }
            __syncthreads();
            if (tid < 64) {
                const int bl = tid & 31;
                float hv[2];
                #pragma unroll
                for (int j = 0; j < 2; ++j) {
                    int nl = (jp + j) * 4;
                    float z[4];
                    #pragma unroll
                    for (int g = 0; g < 4; ++g)
                        z[g] = gbuf[0][bl][nl + g] + gbuf[1][bl][nl + g] +
                               gbuf[2][bl][nl + g] + gbuf[3][bl][nl + g] + bi0[j][g];
                    float ig = 1.f / (1.f + expf(-z[0]));
                    float fg = 1.f / (1.f + expf(-z[1]));
                    float gg = tanhf(z[2]);
                    float og = 1.f / (1.f + expf(-z[3]));
                    float c = fg * c0r[j] + ig * gg;
                    c0r[j] = c;
                    hv[j] = og * tanhf(c);
                }
                union { f16 f[2]; unsigned u; } pk;
                pk.f[0] = (f16)hv[0]; pk.f[1] = (f16)hv[1];
                astore4(H0n + cb_ * 512 + ch, pk.u);
                if (t == T - 1) {
                    out_hT[cb_ * 512 + ch] = hv[0];
                    out_hT[cb_ * 512 + ch + 1] = hv[1];
                    out_cT[cb_ * 512 + ch] = c0r[0];
                    out_cT[cb_ * 512 + ch + 1] = c0r[1];
                }
            }
        }
        dbar(slots, go, ++ep, wg);

        // ================= phase B: lstm1 gates, K=1024 =================
        {
            f32x4 ac0 = {0.f, 0.f, 0.f, 0.f}, ac1 = {0.f, 0.f, 0.f, 0.f};
            const int a0r = (b0 + m16) * 512 + quad * 8;
            const int a1r = (b0 + 16 + m16) * 512 + quad * 8;
            const f16* Asrc = (wv_ < 2) ? H0n : H1t;
            const int k0 = (wv_ & 1) * 256;
            const int gbase = ((wv_ < 2) ? 0 : 64) + (k0 >> 3);
            #pragma unroll
            for (int ks = 0; ks < 8; ++ks) {
                int k = k0 + ks * 32;
                int gr = gbase + ks * 4 + quad, gp = gr ^ (m16 & 7);
                f16x8 w = *(const f16x8*)(WLB + (m16 * 128 + gp) * 8);
                ac0 = MFMA16(*(const f16x8*)(Asrc + a0r + k), w, ac0);
                ac1 = MFMA16(*(const f16x8*)(Asrc + a1r + k), w, ac1);
            }
            #pragma unroll
            for (int r = 0; r < 4; ++r) {
                gbuf[wv_][quad * 4 + r][m16] = ac0[r];
                gbuf[wv_][16 + quad * 4 + r][m16] = ac1[r];
            }
            __syncthreads();
            if (tid < 64) {
                const int bl = tid & 31;
                float hv[2];
                #pragma unroll
                for (int j = 0; j < 2; ++j) {
                    int nl = (jp + j) * 4;
                    float z[4];
                    #pragma unroll
                    for (int g = 0; g < 4; ++g)
                        z[g] = gbuf[0][bl][nl + g] + gbuf[1][bl][nl + g] +
                               gbuf[2][bl][nl + g] + gbuf[3][bl][nl + g] + bi1[j][g];
                    float ig = 1.f / (1.f + expf(-z[0]));
                    float fg = 1.f / (1.f + expf(-z[1]));
                    float gg = tanhf(z[2]);
                    float og = 1.f / (1.f + expf(-z[3]));
                    float c = fg * c1r[j] + ig * gg;
                    c1r[j] = c;
                    hv[j] = og * tanhf(c);
                }
                union { f16 f[2]; unsigned u; } pk;
                pk.f[0] = (f16)hv[0]; pk.f[1] = (f16)hv[1];
                astore4(H1n + cb_ * 512 + ch, pk.u);
                if (t == T - 1) {
                    out_hT[BH + cb_ * 512 + ch] = hv[0];
                    out_hT[BH + cb_ * 512 + ch + 1] = hv[1];
                    out_cT[BH + cb_ * 512 + ch] = c1r[0];
                    out_cT[BH + cb_ * 512 + ch + 1] = c1r[1];
                }
            }
        }
        dbar(slots, go, ++ep, wg);

        // ===== phase C1: scores (all WGs, XCD-local b) + out2 GEMM (xr<16) =
        {
            const f16* hrow = H1n + b_s * 512;
            f16x8 hfrag = *(const f16x8*)(hrow + lane * 8);
            #pragma unroll
            for (int i = 0; i < 5; ++i) {
                int s = soff + wv_ * 5 + i;
                const f16* cr = ctxWV + ((size_t)(b_s * 80 + s)) * 1024 + lane * 8;
                f16x8 a = *(const f16x8*)cr;
                float d = 0.f;
                #pragma unroll
                for (int j = 0; j < 8; ++j) d += (float)a[j] * (float)hfrag[j];
                #pragma unroll
                for (int o = 32; o > 0; o >>= 1) d += __shfl_xor(d, o);
                if (lane == 0) astoref(&scb[b_s * 80 + s], d);
            }
            if (xr < 16) {
                // out2 rows [xid*16,+16), cols [xr*32,+32), K=512 wave-split
                f32x4 ac0 = {0.f, 0.f, 0.f, 0.f}, ac1 = {0.f, 0.f, 0.f, 0.f};
                const int arow = (xid * 16 + m16) * 512 + quad * 8;
                const f16* wr0 = WoutRf + (size_t)(xr * 32 + m16) * 512 + quad * 8;
                const f16* wr1 = WoutRf + (size_t)(xr * 32 + 16 + m16) * 512 + quad * 8;
                const int k0 = wv_ * 128;
                #pragma unroll
                for (int ks = 0; ks < 4; ++ks) {
                    int k = k0 + ks * 32;
                    f16x8 a = *(const f16x8*)(H1n + arow + k);
                    ac0 = MFMA16(a, *(const f16x8*)(wr0 + k), ac0);
                    ac1 = MFMA16(a, *(const f16x8*)(wr1 + k), ac1);
                }
                __syncthreads();
                #pragma unroll
                for (int r = 0; r < 4; ++r) {
                    gbuf[wv_][quad * 4 + r][m16] = ac0[r];       // n-tile 0
                    gbuf[wv_][16 + quad * 4 + r][m16] = ac1[r];  // n-tile 1
                }
                __syncthreads();
                // 256 thr: tile = tid>>7, bl = (tid>>3)&15, np = (tid&7)*2
                const int tile = tid >> 7, bl = (tid >> 3) & 15, np = (tid & 7) * 2;
                const int grow = tile * 16 + bl;    // wait: rows are b, split below
                // gbuf rows: [0..16) = tile0 b-rows, [16..32) = tile1 b-rows
                const int gr0 = tile * 16 + ((tid >> 3) & 15);
                (void)grow;
                float v0 = gbuf[0][gr0][np] + gbuf[1][gr0][np] + gbuf[2][gr0][np] + gbuf[3][gr0][np];
                float v1 = gbuf[0][gr0][np+1] + gbuf[1][gr0][np+1] + gbuf[2][gr0][np+1] + gbuf[3][gr0][np+1];
                union { f16 f[2]; unsigned u; } pk;
                pk.f[0] = (f16)v0; pk.f[1] = (f16)v1;
                const int n = xr * 32 + tile * 16 + np;
                astore4(out2b + (xid * 16 + bl) * 512 + n, pk.u);
            }
        }
        dbar(slots, go, ++ep, wg);

        // ===== phase C2: softmax + ctxV reduce + out half (16<=xr<48) ======
        if (xr >= 16 && xr < 48) {
            if (wv_ == 0 && lane < 40) {
                union { u64 u; float f[2]; } v;
                v.u = aload8(&scb[b2 * 80 + lane * 2]);
                scf[lane * 2] = v.f[0];
                scf[lane * 2 + 1] = v.f[1];
            }
            if (tid < 128)
                o2buf[tid] = aload4((const unsigned*)(out2b + b2 * 512 + nh * 256) + tid);
            __syncthreads();
            if (wv_ == 0) {
                float e0 = scf[lane];
                float e1 = (lane < 16) ? scf[64 + lane] : -1e30f;
                float m = fmaxf(e0, e1);
                #pragma unroll
                for (int o = 32; o > 0; o >>= 1) m = fmaxf(m, __shfl_xor(m, o));
                float x0 = expf(e0 - m);
                float x1 = (lane < 16) ? expf(e1 - m) : 0.f;
                float su = x0 + x1;
                #pragma unroll
                for (int o = 32; o > 0; o >>= 1) su += __shfl_xor(su, o);
                float inv = 1.f / su;
                float p0 = x0 * inv;
                pp[lane] = p0;
                if (nh == 0) out_attn[((size_t)t * 128 + b2) * 80 + lane] = p0;
                if (lane < 16) {
                    float p1 = x1 * inv;
                    pp[64 + lane] = p1;
                    if (nh == 0) out_attn[((size_t)t * 128 + b2) * 80 + 64 + lane] = p1;
                }
            }
            __syncthreads();
            const int n = nh * 256 + tid;
            float acc = 0.f;
            const f16* cv = ctxWV + (size_t)b2 * 80 * 1024 + 512 + n;
            #pragma unroll 8
            for (int s = 0; s < 80; ++s) acc += pp[s] * (float)cv[(size_t)s * 1024];
            float o2 = (float)((const f16*)o2buf)[tid];
            float o = tanhf(acc + o2);
            out_outputs[(size_t)t * BH + b2 * 512 + n] = o;
            obuf[tid] = (f16)o;
            __syncthreads();
            if (tid < 64)
                astore8(XPn + b2 * 512 + nh * 256 + tid * 4, ((const u64*)obuf)[tid]);
        }
        dbar(slots, go, ++ep, wg);
    }
}

// ---------------------------------------------------------------------------
extern "C" void kernel_launch(void* const* d_in, const int* in_sizes, int n_in,
                              void* d_out, int out_size, void* d_ws, size_t ws_size,
                              hipStream_t stream)
{
    const int*   tokens  = (const int*)  d_in[0];
    const float* h0      = (const float*)d_in[1];
    const float* c0      = (const float*)d_in[2];
    const float* context = (const float*)d_in[3];
    const float* embtab  = (const float*)d_in[4];
    const float* Wih0    = (const float*)d_in[5];
    const float* Whh0    = (const float*)d_in[6];
    const float* bih0    = (const float*)d_in[7];
    const float* bhh0    = (const float*)d_in[8];
    const float* Wih1    = (const float*)d_in[9];
    const float* Whh1    = (const float*)d_in[10];
    const float* bih1    = (const float*)d_in[11];
    const float* bhh1    = (const float*)d_in[12];
    const float* Win     = (const float*)d_in[13];
    const float* Wout    = (const float*)d_in[14];

    float* outF        = (float*)d_out;
    float* out_outputs = outF;
    float* out_hT      = outF + (size_t)T * BH;
    float* out_cT      = out_hT + 2 * BH;
    float* out_attn    = out_cT + 2 * BH;

    char* w = (char*)d_ws;
    auto alloc = [&](size_t bytes) {
        char* p = w;
        w += (bytes + 255) & ~(size_t)255;
        return p;
    };
    f16*      WB0a   = (f16*)     alloc((size_t)2048 * 512 * 2);
    f16*      WB0x   = (f16*)     alloc((size_t)2048 * 1024 * 2);
    f16*      WB1p   = (f16*)     alloc((size_t)2048 * 1024 * 2);
    f16*      WoutRf = (f16*)     alloc((size_t)512 * 512 * 2);
    f16*      WcatT  = (f16*)     alloc((size_t)1024 * 512 * 2);
    f16*      embf16 = (f16*)     alloc((size_t)T * B * 512 * 2);
    f16*      ctxWV  = (f16*)     alloc((size_t)B * S * 1024 * 2);
    float*    bsum0  = (float*)   alloc(2048 * 4);
    float*    bsum1  = (float*)   alloc(2048 * 4);
    f16*      h0q    = (f16*)     alloc((size_t)(T + 1) * BH * 2);
    f16*      h1q    = (f16*)     alloc((size_t)(T + 1) * BH * 2);
    f16*      xq     = (f16*)     alloc((size_t)(T + 1) * BH * 2);
    float*    scb    = (float*)   alloc((size_t)B * 80 * 4);
    f16*      out2b  = (f16*)     alloc((size_t)B * 512 * 2);
    unsigned* slots  = (unsigned*)alloc(2048 * 4);
    unsigned* go     = (unsigned*)alloc(256 * 4);

    prep_all<<<1024, 256, 0, stream>>>(Wih0, Whh0, Wih1, Whh1, Wout, Win,
                                       bih0, bhh0, bih1, bhh1, h0,
                                       WB0a, WB0x, WB1p, WoutRf, WcatT,
                                       bsum0, bsum1, h0q, h1q, xq, slots, go);
    prep_emb<<<2048, 256, 0, stream>>>(tokens, embtab, embf16);
    gemm_ctx<<<dim3(32, 320), 256, 0, stream>>>(context, WcatT, ctxWV);

    decoder_persist<<<NWG, 256, 0, stream>>>(
        embf16, WB0a, WB0x, WB1p, WoutRf, ctxWV, bsum0, bsum1, c0,
        h0q, h1q, xq, scb, out2b, slots, go,
        out_outputs, out_attn, out_hT, out_cT);
}